// Round 3
// baseline (259.179 us; speedup 1.0000x reference)
//
#include <hip/hip_runtime.h>
#include <math.h>

// probs/targets: (32,1,512,512) fp32
#define NS 32               // samples
#define NELEM 262144        // elements per sample
#define PB 64               // partial blocks per sample
#define CHUNK (NELEM / PB)  // 4096 elements per block
#define TPB 256             // threads per block (4 waves)
#define GRID (NS * PB)      // 2048 blocks

#define SP (NS * PB)        // 2048 partial sets
#define OFF_S1     0
#define OFF_S2     (SP * 1)
#define OFF_DOT    (SP * 2)
#define OFF_MX     (SP * 3)
#define OFF_CGT    (SP * 4)   // int: count(p > 0.5)
#define OFF_CNT    (SP * 5)   // int: multiplicity of running max
#define OFF_GT     (SP * 6)   // int: count(p > 0.5 at max positions)
#define OFF_TICKET (SP * 7)   // int ticket counter (zeroed via memsetAsync)

__device__ __forceinline__ void combine_max(float& mx, int& cnt, int& gt,
                                            float mx2, int cnt2, int gt2) {
    if (mx2 > mx) { mx = mx2; cnt = cnt2; gt = gt2; }
    else if (mx2 == mx) { cnt += cnt2; gt += gt2; }
}

__global__ __launch_bounds__(TPB) void k_fused(const float* __restrict__ probs,
                                               const float* __restrict__ tgts,
                                               float* __restrict__ wsf,
                                               int* __restrict__ wsi,
                                               int* __restrict__ ticket,
                                               float* __restrict__ out) {
    const int b = blockIdx.x;
    const int s = b >> 6;        // sample
    const int c = b & (PB - 1);  // chunk
    const size_t base = (size_t)s * NELEM + (size_t)c * CHUNK;
    const float4* __restrict__ p4 = (const float4*)(probs + base);
    const float4* __restrict__ t4 = (const float4*)(tgts + base);
    const int t = threadIdx.x;
    const int w = t >> 6, lane = t & 63;

    // ---------------- phase 1: per-block partial reduction ----------------
    float4 pv[4], tv[4];
#pragma unroll
    for (int k = 0; k < 4; ++k) {
        pv[k] = p4[t + k * TPB];
        tv[k] = t4[t + k * TPB];
    }

    float s1[4] = {0.f, 0.f, 0.f, 0.f};
    float s2[4] = {0.f, 0.f, 0.f, 0.f};
    float dt[4] = {0.f, 0.f, 0.f, 0.f};
    float mx[4] = {-INFINITY, -INFINITY, -INFINITY, -INFINITY};
    int cgt[4] = {0, 0, 0, 0}, cnt[4] = {0, 0, 0, 0}, gt[4] = {0, 0, 0, 0};

#pragma unroll
    for (int k = 0; k < 4; ++k) {
        const float pc[4] = {pv[k].x, pv[k].y, pv[k].z, pv[k].w};
        const float tc[4] = {tv[k].x, tv[k].y, tv[k].z, tv[k].w};
#pragma unroll
        for (int j = 0; j < 4; ++j) {
            const float p = pc[j], q = tc[j];
            const int b1 = (p > 0.5f) ? 1 : 0;
            s1[j] += p;
            s2[j] += q;
            dt[j] = fmaf(p, q, dt[j]);
            cgt[j] += b1;
            if (q > mx[j])       { mx[j] = q; cnt[j] = 1; gt[j] = b1; }
            else if (q == mx[j]) { cnt[j] += 1; gt[j] += b1; }
        }
    }

    float rs1 = s1[0] + s1[1] + s1[2] + s1[3];
    float rs2 = s2[0] + s2[1] + s2[2] + s2[3];
    float rdt = dt[0] + dt[1] + dt[2] + dt[3];
    int rcgt = cgt[0] + cgt[1] + cgt[2] + cgt[3];
    float rmx = mx[0]; int rcnt = cnt[0], rgt = gt[0];
#pragma unroll
    for (int j = 1; j < 4; ++j) combine_max(rmx, rcnt, rgt, mx[j], cnt[j], gt[j]);

#pragma unroll
    for (int off = 32; off; off >>= 1) {
        rs1  += __shfl_xor(rs1, off);
        rs2  += __shfl_xor(rs2, off);
        rdt  += __shfl_xor(rdt, off);
        rcgt += __shfl_xor(rcgt, off);
        float m2 = __shfl_xor(rmx, off);
        int   c2 = __shfl_xor(rcnt, off);
        int   g2 = __shfl_xor(rgt, off);
        combine_max(rmx, rcnt, rgt, m2, c2, g2);
    }

    __shared__ float ls1[4], ls2[4], ldt[4], lmx[4];
    __shared__ int   lcg[4], lcn[4], lgt[4];
    if (lane == 0) {
        ls1[w] = rs1; ls2[w] = rs2; ldt[w] = rdt; lmx[w] = rmx;
        lcg[w] = rcgt; lcn[w] = rcnt; lgt[w] = rgt;
    }
    __syncthreads();
    if (t == 0) {
#pragma unroll
        for (int w2 = 1; w2 < TPB / 64; ++w2) {
            rs1 += ls1[w2]; rs2 += ls2[w2]; rdt += ldt[w2]; rcgt += lcg[w2];
            combine_max(rmx, rcnt, rgt, lmx[w2], lcn[w2], lgt[w2]);
        }
        wsf[OFF_S1  + b] = rs1;
        wsf[OFF_S2  + b] = rs2;
        wsf[OFF_DOT + b] = rdt;
        wsf[OFF_MX  + b] = rmx;
        wsi[OFF_CGT + b] = rcgt;
        wsi[OFF_CNT + b] = rcnt;
        wsi[OFF_GT  + b] = rgt;
    }

    // ---------------- ticket: last block finalizes ----------------
    __shared__ int is_last;
    __threadfence();                       // release partials (device scope)
    if (t == 0) {
        int old = atomicAdd(ticket, 1);    // device-scope by default
        is_last = (old == GRID - 1) ? 1 : 0;
    }
    __syncthreads();
    if (!is_last) return;
    __threadfence();                       // acquire all blocks' partials

    // ---------------- phase 2: per-sample finalize (one block) ------------
    __shared__ float scores[NS];
#pragma unroll
    for (int r = 0; r < 8; ++r) {          // wave w handles samples w*8 .. w*8+7
        const int sp = w * 8 + r;
        const int idx = sp * PB + lane;    // lane = partial index (PB == 64)

        float fs1  = wsf[OFF_S1  + idx];
        float fs2  = wsf[OFF_S2  + idx];
        float fdot = wsf[OFF_DOT + idx];
        float fmx  = wsf[OFF_MX  + idx];
        int   fcg  = wsi[OFF_CGT + idx];
        int   fcn  = wsi[OFF_CNT + idx];
        int   fgt  = wsi[OFF_GT  + idx];

#pragma unroll
        for (int off = 32; off; off >>= 1) {
            fs1  += __shfl_xor(fs1, off);
            fs2  += __shfl_xor(fs2, off);
            fdot += __shfl_xor(fdot, off);
            fcg  += __shfl_xor(fcg, off);
            float m2 = __shfl_xor(fmx, off);
            int   c2 = __shfl_xor(fcn, off);
            int   g2 = __shfl_xor(fgt, off);
            combine_max(fmx, fcn, fgt, m2, c2, g2);
        }

        if (lane == 0) {
            const int cle = NELEM - fcg;   // count(p <= 0.5)
            const long long corr = (long long)cle - (long long)fcn + 2LL * (long long)fgt;
            float score = 2.0f * (fdot + 1.0f) / (fs1 + fs2 + 1.0f);
            if (corr == 1) score = 1.0f;   // acc == 1.0 (probs.shape[1] == 1)
            scores[sp] = 1.0f - score;
        }
    }

    __syncthreads();
    if (t < 64) {
        float v = (t < NS) ? scores[t] : 0.0f;
#pragma unroll
        for (int off = 32; off; off >>= 1) v += __shfl_xor(v, off);
        if (t == 0) out[0] = v * (1.0f / (float)NS);
    }
}

extern "C" void kernel_launch(void* const* d_in, const int* in_sizes, int n_in,
                              void* d_out, int out_size, void* d_ws, size_t ws_size,
                              hipStream_t stream) {
    const float* probs = (const float*)d_in[0];
    const float* tgts  = (const float*)d_in[1];
    float* wsf = (float*)d_ws;
    int*   wsi = (int*)d_ws;
    float* out = (float*)d_out;

    // zero the ticket counter (graph-capturable, deterministic each launch)
    hipMemsetAsync((void*)(wsi + OFF_TICKET), 0, sizeof(int), stream);
    k_fused<<<GRID, TPB, 0, stream>>>(probs, tgts, wsf, wsi, wsi + OFF_TICKET, out);
}

// Round 4
// 60.464 us; speedup vs baseline: 4.2865x; 4.2865x over previous
//
#include <hip/hip_runtime.h>
#include <math.h>

// probs/targets: (32,1,512,512) fp32
// ROUND 4 = CALIBRATION: identical round-2 kernels, but k_partial launched 4x
// (idempotent). dur_4 = overhead + 4*T_p + T_f; round-2 dur_1 = 23.1 us
// => T_p = (dur_4 - 23.1)/3. Discriminates overhead-bound vs partial-bound.
#define NS 32               // samples
#define NELEM 262144        // elements per sample
#define PB 64               // partial blocks per sample
#define CHUNK (NELEM / PB)  // 4096 elements per block
#define TPB 256             // threads per block (4 waves)

#define SP (NS * PB)        // 2048 partial sets
#define OFF_S1   0
#define OFF_S2   (SP * 1)
#define OFF_DOT  (SP * 2)
#define OFF_MX   (SP * 3)
#define OFF_CGT  (SP * 4)   // int: count(p > 0.5)
#define OFF_CNT  (SP * 5)   // int: multiplicity of running max
#define OFF_GT   (SP * 6)   // int: count(p > 0.5 at max positions)

__device__ __forceinline__ void combine_max(float& mx, int& cnt, int& gt,
                                            float mx2, int cnt2, int gt2) {
    if (mx2 > mx) { mx = mx2; cnt = cnt2; gt = gt2; }
    else if (mx2 == mx) { cnt += cnt2; gt += gt2; }
}

__global__ __launch_bounds__(TPB) void k_partial(const float* __restrict__ probs,
                                                 const float* __restrict__ tgts,
                                                 float* __restrict__ wsf,
                                                 int* __restrict__ wsi) {
    const int b = blockIdx.x;
    const int s = b >> 6;        // sample
    const int c = b & (PB - 1);  // chunk
    const size_t base = (size_t)s * NELEM + (size_t)c * CHUNK;
    const float4* __restrict__ p4 = (const float4*)(probs + base);
    const float4* __restrict__ t4 = (const float4*)(tgts + base);
    const int t = threadIdx.x;

    float4 pv[4], tv[4];
#pragma unroll
    for (int k = 0; k < 4; ++k) {
        pv[k] = p4[t + k * TPB];
        tv[k] = t4[t + k * TPB];
    }

    float s1[4] = {0.f, 0.f, 0.f, 0.f};
    float s2[4] = {0.f, 0.f, 0.f, 0.f};
    float dt[4] = {0.f, 0.f, 0.f, 0.f};
    float mx[4] = {-INFINITY, -INFINITY, -INFINITY, -INFINITY};
    int cgt[4] = {0, 0, 0, 0}, cnt[4] = {0, 0, 0, 0}, gt[4] = {0, 0, 0, 0};

#pragma unroll
    for (int k = 0; k < 4; ++k) {
        const float pc[4] = {pv[k].x, pv[k].y, pv[k].z, pv[k].w};
        const float tc[4] = {tv[k].x, tv[k].y, tv[k].z, tv[k].w};
#pragma unroll
        for (int j = 0; j < 4; ++j) {
            const float p = pc[j], q = tc[j];
            const int b1 = (p > 0.5f) ? 1 : 0;
            s1[j] += p;
            s2[j] += q;
            dt[j] = fmaf(p, q, dt[j]);
            cgt[j] += b1;
            if (q > mx[j])       { mx[j] = q; cnt[j] = 1; gt[j] = b1; }
            else if (q == mx[j]) { cnt[j] += 1; gt[j] += b1; }
        }
    }

    float rs1 = s1[0] + s1[1] + s1[2] + s1[3];
    float rs2 = s2[0] + s2[1] + s2[2] + s2[3];
    float rdt = dt[0] + dt[1] + dt[2] + dt[3];
    int rcgt = cgt[0] + cgt[1] + cgt[2] + cgt[3];
    float rmx = mx[0]; int rcnt = cnt[0], rgt = gt[0];
#pragma unroll
    for (int j = 1; j < 4; ++j) combine_max(rmx, rcnt, rgt, mx[j], cnt[j], gt[j]);

#pragma unroll
    for (int off = 32; off; off >>= 1) {
        rs1  += __shfl_xor(rs1, off);
        rs2  += __shfl_xor(rs2, off);
        rdt  += __shfl_xor(rdt, off);
        rcgt += __shfl_xor(rcgt, off);
        float m2 = __shfl_xor(rmx, off);
        int   c2 = __shfl_xor(rcnt, off);
        int   g2 = __shfl_xor(rgt, off);
        combine_max(rmx, rcnt, rgt, m2, c2, g2);
    }

    __shared__ float ls1[4], ls2[4], ldt[4], lmx[4];
    __shared__ int   lcg[4], lcn[4], lgt[4];
    const int w = t >> 6, lane = t & 63;
    if (lane == 0) {
        ls1[w] = rs1; ls2[w] = rs2; ldt[w] = rdt; lmx[w] = rmx;
        lcg[w] = rcgt; lcn[w] = rcnt; lgt[w] = rgt;
    }
    __syncthreads();
    if (t == 0) {
#pragma unroll
        for (int w2 = 1; w2 < TPB / 64; ++w2) {
            rs1 += ls1[w2]; rs2 += ls2[w2]; rdt += ldt[w2]; rcgt += lcg[w2];
            combine_max(rmx, rcnt, rgt, lmx[w2], lcn[w2], lgt[w2]);
        }
        wsf[OFF_S1  + b] = rs1;
        wsf[OFF_S2  + b] = rs2;
        wsf[OFF_DOT + b] = rdt;
        wsf[OFF_MX  + b] = rmx;
        wsi[OFF_CGT + b] = rcgt;
        wsi[OFF_CNT + b] = rcnt;
        wsi[OFF_GT  + b] = rgt;
    }
}

__global__ __launch_bounds__(1024) void k_final(const float* __restrict__ wsf,
                                                const int* __restrict__ wsi,
                                                float* __restrict__ out) {
    __shared__ float scores[NS];
    const int t = threadIdx.x;
    const int w = t >> 6, lane = t & 63;

#pragma unroll
    for (int r = 0; r < 2; ++r) {
        const int s = w * 2 + r;
        const int idx = s * PB + lane;

        float s1  = wsf[OFF_S1  + idx];
        float s2  = wsf[OFF_S2  + idx];
        float dot = wsf[OFF_DOT + idx];
        float mx  = wsf[OFF_MX  + idx];
        int   cgt = wsi[OFF_CGT + idx];
        int   cnt = wsi[OFF_CNT + idx];
        int   gt  = wsi[OFF_GT  + idx];

#pragma unroll
        for (int off = 32; off; off >>= 1) {
            s1  += __shfl_xor(s1, off);
            s2  += __shfl_xor(s2, off);
            dot += __shfl_xor(dot, off);
            cgt += __shfl_xor(cgt, off);
            float m2 = __shfl_xor(mx, off);
            int   c2 = __shfl_xor(cnt, off);
            int   g2 = __shfl_xor(gt, off);
            combine_max(mx, cnt, gt, m2, c2, g2);
        }

        if (lane == 0) {
            const int cle = NELEM - cgt;
            const long long corr = (long long)cle - (long long)cnt + 2LL * (long long)gt;
            float score = 2.0f * (dot + 1.0f) / (s1 + s2 + 1.0f);
            if (corr == 1) score = 1.0f;  // acc == 1.0 branch (shape[1] == 1)
            scores[s] = 1.0f - score;
        }
    }

    __syncthreads();
    if (t < 64) {
        float v = (t < NS) ? scores[t] : 0.0f;
#pragma unroll
        for (int off = 32; off; off >>= 1) v += __shfl_xor(v, off);
        if (t == 0) out[0] = v * (1.0f / (float)NS);
    }
}

extern "C" void kernel_launch(void* const* d_in, const int* in_sizes, int n_in,
                              void* d_out, int out_size, void* d_ws, size_t ws_size,
                              hipStream_t stream) {
    const float* probs = (const float*)d_in[0];
    const float* tgts  = (const float*)d_in[1];
    float* wsf = (float*)d_ws;
    int*   wsi = (int*)d_ws;
    float* out = (float*)d_out;

    // CALIBRATION: 4 idempotent replays of k_partial to measure T_p.
    // dur_4 = overhead + 4*T_p + T_f;  T_p = (dur_4 - 23.1us)/3.
    for (int i = 0; i < 4; ++i)
        k_partial<<<NS * PB, TPB, 0, stream>>>(probs, tgts, wsf, wsi);
    k_final<<<1, 1024, 0, stream>>>(wsf, wsi, out);
}

// Round 5
// 27.985 us; speedup vs baseline: 9.2614x; 2.1606x over previous
//
#include <hip/hip_runtime.h>
#include <math.h>

// probs/targets: (32,1,512,512) fp32
// ROUND 5 = A/B PROBE: k_probe is a minimal pure-read kernel with IDENTICAL
// geometry/addressing to k_partial but ~no compute. Serialized pipeline:
//   dur = (OH + T_p + T_f) + T_probe = 23.08 + T_probe.
// T_probe ~= 12.4 -> 5.4 TB/s is the 2-stream read ceiling (declare roofline).
// T_probe ~= 10   -> ~2.5us of kernel-internal overhead in k_partial to chase.
#define NS 32
#define NELEM 262144
#define PB 64
#define CHUNK (NELEM / PB)  // 4096
#define TPB 256

#define SP (NS * PB)        // 2048 partial sets
#define OFF_S1   0
#define OFF_S2   (SP * 1)
#define OFF_DOT  (SP * 2)
#define OFF_MX   (SP * 3)
#define OFF_CGT  (SP * 4)
#define OFF_CNT  (SP * 5)
#define OFF_GT   (SP * 6)
#define OFF_PROBE (SP * 8)  // probe sink — never read by k_final

__device__ __forceinline__ void combine_max(float& mx, int& cnt, int& gt,
                                            float mx2, int cnt2, int gt2) {
    if (mx2 > mx) { mx = mx2; cnt = cnt2; gt = gt2; }
    else if (mx2 == mx) { cnt += cnt2; gt += gt2; }
}

// ---------- minimal pure-read probe: same addressing as k_partial ----------
__global__ __launch_bounds__(TPB) void k_probe(const float* __restrict__ probs,
                                               const float* __restrict__ tgts,
                                               float* __restrict__ sink) {
    const int b = blockIdx.x;
    const int s = b >> 6;
    const int c = b & (PB - 1);
    const size_t base = (size_t)s * NELEM + (size_t)c * CHUNK;
    const float4* __restrict__ p4 = (const float4*)(probs + base);
    const float4* __restrict__ t4 = (const float4*)(tgts + base);
    const int t = threadIdx.x;

    float4 pv[4], tv[4];
#pragma unroll
    for (int k = 0; k < 4; ++k) {
        pv[k] = p4[t + k * TPB];
        tv[k] = t4[t + k * TPB];
    }
    // minimal consumption: 8 float4 adds (32 VALU), horizontal sum, masked store
    float4 ap = {0.f, 0.f, 0.f, 0.f}, at = {0.f, 0.f, 0.f, 0.f};
#pragma unroll
    for (int k = 0; k < 4; ++k) {
        ap.x += pv[k].x; ap.y += pv[k].y; ap.z += pv[k].z; ap.w += pv[k].w;
        at.x += tv[k].x; at.y += tv[k].y; at.z += tv[k].z; at.w += tv[k].w;
    }
    float v = (ap.x + ap.y) + (ap.z + ap.w) + (at.x + at.y) + (at.z + at.w);
    if (t == 0) sink[b] = v;   // exec-masked store; all lanes' loads stay live
}

// ---------------- round-2 k_partial (unchanged) ----------------
__global__ __launch_bounds__(TPB) void k_partial(const float* __restrict__ probs,
                                                 const float* __restrict__ tgts,
                                                 float* __restrict__ wsf,
                                                 int* __restrict__ wsi) {
    const int b = blockIdx.x;
    const int s = b >> 6;
    const int c = b & (PB - 1);
    const size_t base = (size_t)s * NELEM + (size_t)c * CHUNK;
    const float4* __restrict__ p4 = (const float4*)(probs + base);
    const float4* __restrict__ t4 = (const float4*)(tgts + base);
    const int t = threadIdx.x;

    float4 pv[4], tv[4];
#pragma unroll
    for (int k = 0; k < 4; ++k) {
        pv[k] = p4[t + k * TPB];
        tv[k] = t4[t + k * TPB];
    }

    float s1[4] = {0.f, 0.f, 0.f, 0.f};
    float s2[4] = {0.f, 0.f, 0.f, 0.f};
    float dt[4] = {0.f, 0.f, 0.f, 0.f};
    float mx[4] = {-INFINITY, -INFINITY, -INFINITY, -INFINITY};
    int cgt[4] = {0, 0, 0, 0}, cnt[4] = {0, 0, 0, 0}, gt[4] = {0, 0, 0, 0};

#pragma unroll
    for (int k = 0; k < 4; ++k) {
        const float pc[4] = {pv[k].x, pv[k].y, pv[k].z, pv[k].w};
        const float tc[4] = {tv[k].x, tv[k].y, tv[k].z, tv[k].w};
#pragma unroll
        for (int j = 0; j < 4; ++j) {
            const float p = pc[j], q = tc[j];
            const int b1 = (p > 0.5f) ? 1 : 0;
            s1[j] += p;
            s2[j] += q;
            dt[j] = fmaf(p, q, dt[j]);
            cgt[j] += b1;
            if (q > mx[j])       { mx[j] = q; cnt[j] = 1; gt[j] = b1; }
            else if (q == mx[j]) { cnt[j] += 1; gt[j] += b1; }
        }
    }

    float rs1 = s1[0] + s1[1] + s1[2] + s1[3];
    float rs2 = s2[0] + s2[1] + s2[2] + s2[3];
    float rdt = dt[0] + dt[1] + dt[2] + dt[3];
    int rcgt = cgt[0] + cgt[1] + cgt[2] + cgt[3];
    float rmx = mx[0]; int rcnt = cnt[0], rgt = gt[0];
#pragma unroll
    for (int j = 1; j < 4; ++j) combine_max(rmx, rcnt, rgt, mx[j], cnt[j], gt[j]);

#pragma unroll
    for (int off = 32; off; off >>= 1) {
        rs1  += __shfl_xor(rs1, off);
        rs2  += __shfl_xor(rs2, off);
        rdt  += __shfl_xor(rdt, off);
        rcgt += __shfl_xor(rcgt, off);
        float m2 = __shfl_xor(rmx, off);
        int   c2 = __shfl_xor(rcnt, off);
        int   g2 = __shfl_xor(rgt, off);
        combine_max(rmx, rcnt, rgt, m2, c2, g2);
    }

    __shared__ float ls1[4], ls2[4], ldt[4], lmx[4];
    __shared__ int   lcg[4], lcn[4], lgt[4];
    const int w = t >> 6, lane = t & 63;
    if (lane == 0) {
        ls1[w] = rs1; ls2[w] = rs2; ldt[w] = rdt; lmx[w] = rmx;
        lcg[w] = rcgt; lcn[w] = rcnt; lgt[w] = rgt;
    }
    __syncthreads();
    if (t == 0) {
#pragma unroll
        for (int w2 = 1; w2 < TPB / 64; ++w2) {
            rs1 += ls1[w2]; rs2 += ls2[w2]; rdt += ldt[w2]; rcgt += lcg[w2];
            combine_max(rmx, rcnt, rgt, lmx[w2], lcn[w2], lgt[w2]);
        }
        wsf[OFF_S1  + b] = rs1;
        wsf[OFF_S2  + b] = rs2;
        wsf[OFF_DOT + b] = rdt;
        wsf[OFF_MX  + b] = rmx;
        wsi[OFF_CGT + b] = rcgt;
        wsi[OFF_CNT + b] = rcnt;
        wsi[OFF_GT  + b] = rgt;
    }
}

__global__ __launch_bounds__(1024) void k_final(const float* __restrict__ wsf,
                                                const int* __restrict__ wsi,
                                                float* __restrict__ out) {
    __shared__ float scores[NS];
    const int t = threadIdx.x;
    const int w = t >> 6, lane = t & 63;

#pragma unroll
    for (int r = 0; r < 2; ++r) {
        const int s = w * 2 + r;
        const int idx = s * PB + lane;

        float s1  = wsf[OFF_S1  + idx];
        float s2  = wsf[OFF_S2  + idx];
        float dot = wsf[OFF_DOT + idx];
        float mx  = wsf[OFF_MX  + idx];
        int   cgt = wsi[OFF_CGT + idx];
        int   cnt = wsi[OFF_CNT + idx];
        int   gt  = wsi[OFF_GT  + idx];

#pragma unroll
        for (int off = 32; off; off >>= 1) {
            s1  += __shfl_xor(s1, off);
            s2  += __shfl_xor(s2, off);
            dot += __shfl_xor(dot, off);
            cgt += __shfl_xor(cgt, off);
            float m2 = __shfl_xor(mx, off);
            int   c2 = __shfl_xor(cnt, off);
            int   g2 = __shfl_xor(gt, off);
            combine_max(mx, cnt, gt, m2, c2, g2);
        }

        if (lane == 0) {
            const int cle = NELEM - cgt;
            const long long corr = (long long)cle - (long long)cnt + 2LL * (long long)gt;
            float score = 2.0f * (dot + 1.0f) / (s1 + s2 + 1.0f);
            if (corr == 1) score = 1.0f;
            scores[s] = 1.0f - score;
        }
    }

    __syncthreads();
    if (t < 64) {
        float v = (t < NS) ? scores[t] : 0.0f;
#pragma unroll
        for (int off = 32; off; off >>= 1) v += __shfl_xor(v, off);
        if (t == 0) out[0] = v * (1.0f / (float)NS);
    }
}

extern "C" void kernel_launch(void* const* d_in, const int* in_sizes, int n_in,
                              void* d_out, int out_size, void* d_ws, size_t ws_size,
                              hipStream_t stream) {
    const float* probs = (const float*)d_in[0];
    const float* tgts  = (const float*)d_in[1];
    float* wsf = (float*)d_ws;
    int*   wsi = (int*)d_ws;
    float* out = (float*)d_out;

    // A/B probe: minimal pure-read kernel, identical geometry (idempotent,
    // writes scratch only). dur = 23.08us + T_probe.
    k_probe<<<NS * PB, TPB, 0, stream>>>(probs, tgts, wsf + OFF_PROBE);
    k_partial<<<NS * PB, TPB, 0, stream>>>(probs, tgts, wsf, wsi);
    k_final<<<1, 1024, 0, stream>>>(wsf, wsi, out);
}

// Round 6
// 22.560 us; speedup vs baseline: 11.4882x; 1.2404x over previous
//
#include <hip/hip_runtime.h>
#include <math.h>

// probs/targets: (32,1,512,512) fp32
// ROUND 6: two-pass-in-registers max counting (branch-free), packed (cnt|gt).
// Probe established: inputs L3-resident during replays (~4.9us read floor);
// round-2 k_partial was compute-heavy (12.46us). This cuts VALU ~2x and kills
// the loop-carried max-update chains + divergent branches.
#define NS 32
#define NELEM 262144
#define PB 64
#define CHUNK (NELEM / PB)  // 4096 elements per block
#define TPB 256             // 4 waves; 16 elements per thread

#define SP (NS * PB)        // 2048 partial sets
#define OFF_S1   0
#define OFF_S2   (SP * 1)
#define OFF_DOT  (SP * 2)
#define OFF_MX   (SP * 3)
#define OFF_CGT  (SP * 4)   // int: count(p > 0.5) per block
#define OFF_PK   (SP * 5)   // int: (cnt_at_max << 16) | gt_at_max

// combine (mx,pk) semigroup: on strictly-greater replace, on equal add.
// cnt,gt <= 4096 at block scope -> 16-bit fields never overflow here.
__device__ __forceinline__ void comb(float& mx, int& pk, float m2, int pk2) {
    const bool g = m2 > mx;
    const bool e = m2 == mx;
    pk = g ? pk2 : (pk + (e ? pk2 : 0));
    mx = fmaxf(mx, m2);
}

__global__ __launch_bounds__(TPB) void k_partial(const float* __restrict__ probs,
                                                 const float* __restrict__ tgts,
                                                 float* __restrict__ wsf,
                                                 int* __restrict__ wsi) {
    const int b = blockIdx.x;
    const int s = b >> 6;        // sample
    const int c = b & (PB - 1);  // chunk
    const size_t base = (size_t)s * NELEM + (size_t)c * CHUNK;
    const float4* __restrict__ p4 = (const float4*)(probs + base);
    const float4* __restrict__ t4 = (const float4*)(tgts + base);
    const int t = threadIdx.x;

    float4 pv[4], tv[4];
#pragma unroll
    for (int k = 0; k < 4; ++k) {
        pv[k] = p4[t + k * TPB];
        tv[k] = t4[t + k * TPB];
    }

    // ---- pass A: straight-line sums (component-parallel, no chains) ----
    float4 a1 = {0.f,0.f,0.f,0.f}, a2 = {0.f,0.f,0.f,0.f}, ad = {0.f,0.f,0.f,0.f};
#pragma unroll
    for (int k = 0; k < 4; ++k) {
        a1.x += pv[k].x; a1.y += pv[k].y; a1.z += pv[k].z; a1.w += pv[k].w;
        a2.x += tv[k].x; a2.y += tv[k].y; a2.z += tv[k].z; a2.w += tv[k].w;
        ad.x = fmaf(pv[k].x, tv[k].x, ad.x);
        ad.y = fmaf(pv[k].y, tv[k].y, ad.y);
        ad.z = fmaf(pv[k].z, tv[k].z, ad.z);
        ad.w = fmaf(pv[k].w, tv[k].w, ad.w);
    }
    float s1 = (a1.x + a1.y) + (a1.z + a1.w);
    float s2 = (a2.x + a2.y) + (a2.z + a2.w);
    float dt = (ad.x + ad.y) + (ad.z + ad.w);

    // ---- pass B: thread-local max via pairwise tree (depth 4) ----
    float mk[4];
#pragma unroll
    for (int k = 0; k < 4; ++k)
        mk[k] = fmaxf(fmaxf(tv[k].x, tv[k].y), fmaxf(tv[k].z, tv[k].w));
    const float mx = fmaxf(fmaxf(mk[0], mk[1]), fmaxf(mk[2], mk[3]));

    // ---- pass C: branch-free recount vs thread-local max ----
    int cgt = 0, cnt = 0, gt = 0;
#pragma unroll
    for (int k = 0; k < 4; ++k) {
        const float pc[4] = {pv[k].x, pv[k].y, pv[k].z, pv[k].w};
        const float tc[4] = {tv[k].x, tv[k].y, tv[k].z, tv[k].w};
#pragma unroll
        for (int j = 0; j < 4; ++j) {
            const int b1 = pc[j] > 0.5f;
            const int eq = tc[j] == mx;
            cgt += b1;
            cnt += eq;
            gt  += eq & b1;
        }
    }
    int pk = (cnt << 16) | gt;

    // ---- wave butterfly (6 quantities) ----
    float rmx = mx; int rpk = pk;
#pragma unroll
    for (int off = 32; off; off >>= 1) {
        s1  += __shfl_xor(s1, off);
        s2  += __shfl_xor(s2, off);
        dt  += __shfl_xor(dt, off);
        cgt += __shfl_xor(cgt, off);
        const float m2 = __shfl_xor(rmx, off);
        const int  pk2 = __shfl_xor(rpk, off);
        comb(rmx, rpk, m2, pk2);
    }

    // ---- cross-wave via LDS (4 waves) ----
    __shared__ float ls1[4], ls2[4], ldt[4], lmx[4];
    __shared__ int   lcg[4], lpk[4];
    const int w = t >> 6, lane = t & 63;
    if (lane == 0) {
        ls1[w] = s1; ls2[w] = s2; ldt[w] = dt; lmx[w] = rmx;
        lcg[w] = cgt; lpk[w] = rpk;
    }
    __syncthreads();
    if (t == 0) {
#pragma unroll
        for (int w2 = 1; w2 < TPB / 64; ++w2) {
            s1 += ls1[w2]; s2 += ls2[w2]; dt += ldt[w2]; cgt += lcg[w2];
            comb(rmx, rpk, lmx[w2], lpk[w2]);
        }
        wsf[OFF_S1  + b] = s1;
        wsf[OFF_S2  + b] = s2;
        wsf[OFF_DOT + b] = dt;
        wsf[OFF_MX  + b] = rmx;
        wsi[OFF_CGT + b] = cgt;
        wsi[OFF_PK  + b] = rpk;
    }
}

__device__ __forceinline__ void combine_max(float& mx, int& cnt, int& gt,
                                            float mx2, int cnt2, int gt2) {
    if (mx2 > mx) { mx = mx2; cnt = cnt2; gt = gt2; }
    else if (mx2 == mx) { cnt += cnt2; gt += gt2; }
}

// Fused finalize + mean: 1 block, 1024 threads; wave w reduces samples 2w,2w+1.
__global__ __launch_bounds__(1024) void k_final(const float* __restrict__ wsf,
                                                const int* __restrict__ wsi,
                                                float* __restrict__ out) {
    __shared__ float scores[NS];
    const int t = threadIdx.x;
    const int w = t >> 6, lane = t & 63;

#pragma unroll
    for (int r = 0; r < 2; ++r) {
        const int s = w * 2 + r;
        const int idx = s * PB + lane;

        float s1  = wsf[OFF_S1  + idx];
        float s2  = wsf[OFF_S2  + idx];
        float dot = wsf[OFF_DOT + idx];
        float mx  = wsf[OFF_MX  + idx];
        int   cgt = wsi[OFF_CGT + idx];
        const int pk = wsi[OFF_PK + idx];
        int   cnt = pk >> 16;          // unpack: sample-level sums may exceed
        int   gt  = pk & 0xFFFF;       // 16 bits, so reduce unpacked here

#pragma unroll
        for (int off = 32; off; off >>= 1) {
            s1  += __shfl_xor(s1, off);
            s2  += __shfl_xor(s2, off);
            dot += __shfl_xor(dot, off);
            cgt += __shfl_xor(cgt, off);
            float m2 = __shfl_xor(mx, off);
            int   c2 = __shfl_xor(cnt, off);
            int   g2 = __shfl_xor(gt, off);
            combine_max(mx, cnt, gt, m2, c2, g2);
        }

        if (lane == 0) {
            const int cle = NELEM - cgt;   // count(p <= 0.5)
            const long long corr = (long long)cle - (long long)cnt + 2LL * (long long)gt;
            float score = 2.0f * (dot + 1.0f) / (s1 + s2 + 1.0f);
            if (corr == 1) score = 1.0f;   // acc == 1.0 (probs.shape[1] == 1)
            scores[s] = 1.0f - score;
        }
    }

    __syncthreads();
    if (t < 64) {
        float v = (t < NS) ? scores[t] : 0.0f;
#pragma unroll
        for (int off = 32; off; off >>= 1) v += __shfl_xor(v, off);
        if (t == 0) out[0] = v * (1.0f / (float)NS);
    }
}

extern "C" void kernel_launch(void* const* d_in, const int* in_sizes, int n_in,
                              void* d_out, int out_size, void* d_ws, size_t ws_size,
                              hipStream_t stream) {
    const float* probs = (const float*)d_in[0];
    const float* tgts  = (const float*)d_in[1];
    float* wsf = (float*)d_ws;
    int*   wsi = (int*)d_ws;
    float* out = (float*)d_out;

    k_partial<<<NS * PB, TPB, 0, stream>>>(probs, tgts, wsf, wsi);
    k_final<<<1, 1024, 0, stream>>>(wsf, wsi, out);
}

// Round 7
// 19.262 us; speedup vs baseline: 13.4554x; 1.1712x over previous
//
#include <hip/hip_runtime.h>
#include <math.h>

// probs/targets: (32,1,512,512) fp32
// ROUND 7: amortize the DS-pipe reduction tail. Evidence: T_p - T_probe =
// 7.6us survived halving VALU (r6: -0.5us) => shuffle butterfly is LDS-pipe
// throughput-bound (~5.8cyc/op, one pipe/CU, 32 waves/CU in lockstep).
// Fix: 64 elements/thread (was 16) -> 4x fewer waves -> 4x fewer DS ops.
#define NS 32
#define NELEM 262144
#define PBLK 16               // partial blocks per sample
#define GRID (NS * PBLK)      // 512 blocks
#define TPB 256               // 4 waves
#define CHUNK (NELEM / PBLK)  // 16384 elements per block; 64 per thread

#define NPART (NS * PBLK)     // 512 partial sets
#define OFF_S1   0
#define OFF_S2   (NPART * 1)
#define OFF_DOT  (NPART * 2)
#define OFF_MX   (NPART * 3)
#define OFF_CGT  (NPART * 4)  // int: count(p > 0.5)
#define OFF_PK   (NPART * 5)  // int: (cnt_at_max << 16) | gt_at_max

// branch-free (mx,pk) semigroup combine; fields never overflow at block
// scope (counts of disjoint subsets of the block's 16384 elements)
__device__ __forceinline__ void comb(float& mx, int& pk, float m2, int pk2) {
    const bool g = m2 > mx;
    const bool e = m2 == mx;
    pk = g ? pk2 : (pk + (e ? pk2 : 0));
    mx = fmaxf(mx, m2);
}

__global__ __launch_bounds__(TPB) void k_partial(const float* __restrict__ probs,
                                                 const float* __restrict__ tgts,
                                                 float* __restrict__ wsf,
                                                 int* __restrict__ wsi) {
    const int b = blockIdx.x;
    const int s = b >> 4;           // sample
    const int c = b & (PBLK - 1);   // chunk within sample
    const size_t base = (size_t)s * NELEM + (size_t)c * CHUNK;
    const float4* __restrict__ p4 = (const float4*)(probs + base);
    const float4* __restrict__ t4 = (const float4*)(tgts + base);
    const int t = threadIdx.x;

    // persistent component-parallel accumulators
    float4 a1 = {0.f,0.f,0.f,0.f}, a2 = {0.f,0.f,0.f,0.f}, ad = {0.f,0.f,0.f,0.f};
    int cgt = 0;
    float mxr = -INFINITY;
    int pkr = 0;

    // 4 groups x (4 float4-pairs) = 64 elements/thread, coalesced
#pragma unroll
    for (int g = 0; g < 4; ++g) {
        float4 pv[4], tv[4];
#pragma unroll
        for (int k = 0; k < 4; ++k) {
            const int idx = g * 1024 + k * 256 + t;
            pv[k] = p4[idx];
            tv[k] = t4[idx];
        }

        // sums (no loop-carried scalar chains)
#pragma unroll
        for (int k = 0; k < 4; ++k) {
            a1.x += pv[k].x; a1.y += pv[k].y; a1.z += pv[k].z; a1.w += pv[k].w;
            a2.x += tv[k].x; a2.y += tv[k].y; a2.z += tv[k].z; a2.w += tv[k].w;
            ad.x = fmaf(pv[k].x, tv[k].x, ad.x);
            ad.y = fmaf(pv[k].y, tv[k].y, ad.y);
            ad.z = fmaf(pv[k].z, tv[k].z, ad.z);
            ad.w = fmaf(pv[k].w, tv[k].w, ad.w);
        }

        // group max via pairwise tree
        float4 mm;
        mm.x = fmaxf(fmaxf(tv[0].x, tv[1].x), fmaxf(tv[2].x, tv[3].x));
        mm.y = fmaxf(fmaxf(tv[0].y, tv[1].y), fmaxf(tv[2].y, tv[3].y));
        mm.z = fmaxf(fmaxf(tv[0].z, tv[1].z), fmaxf(tv[2].z, tv[3].z));
        mm.w = fmaxf(fmaxf(tv[0].w, tv[1].w), fmaxf(tv[2].w, tv[3].w));
        const float mg = fmaxf(fmaxf(mm.x, mm.y), fmaxf(mm.z, mm.w));

        // branch-free recount vs group max (reuses p>0.5 compares for cgt)
        int cp = 0, cg = 0, gg = 0;
#pragma unroll
        for (int k = 0; k < 4; ++k) {
            const float pc[4] = {pv[k].x, pv[k].y, pv[k].z, pv[k].w};
            const float tc[4] = {tv[k].x, tv[k].y, tv[k].z, tv[k].w};
#pragma unroll
            for (int j = 0; j < 4; ++j) {
                const int b1 = pc[j] > 0.5f;
                const int eq = tc[j] == mg;
                cp += b1;
                cg += eq;
                gg += eq & b1;
            }
        }
        cgt += cp;
        comb(mxr, pkr, mg, (cg << 16) | gg);   // 4-op fold, depth-4 chain total
    }

    float s1 = (a1.x + a1.y) + (a1.z + a1.w);
    float s2 = (a2.x + a2.y) + (a2.z + a2.w);
    float dt = (ad.x + ad.y) + (ad.z + ad.w);

    // wave butterfly: 6 quantities x 6 levels (now only 4 waves/block, 512 blocks)
#pragma unroll
    for (int off = 32; off; off >>= 1) {
        s1  += __shfl_xor(s1, off);
        s2  += __shfl_xor(s2, off);
        dt  += __shfl_xor(dt, off);
        cgt += __shfl_xor(cgt, off);
        const float m2 = __shfl_xor(mxr, off);
        const int  pk2 = __shfl_xor(pkr, off);
        comb(mxr, pkr, m2, pk2);
    }

    // cross-wave via LDS (4 waves)
    __shared__ float ls1[4], ls2[4], ldt[4], lmx[4];
    __shared__ int   lcg[4], lpk[4];
    const int w = t >> 6, lane = t & 63;
    if (lane == 0) {
        ls1[w] = s1; ls2[w] = s2; ldt[w] = dt; lmx[w] = mxr;
        lcg[w] = cgt; lpk[w] = pkr;
    }
    __syncthreads();
    if (t == 0) {
#pragma unroll
        for (int w2 = 1; w2 < TPB / 64; ++w2) {
            s1 += ls1[w2]; s2 += ls2[w2]; dt += ldt[w2]; cgt += lcg[w2];
            comb(mxr, pkr, lmx[w2], lpk[w2]);
        }
        wsf[OFF_S1  + b] = s1;
        wsf[OFF_S2  + b] = s2;
        wsf[OFF_DOT + b] = dt;
        wsf[OFF_MX  + b] = mxr;
        wsi[OFF_CGT + b] = cgt;
        wsi[OFF_PK  + b] = pkr;
    }
}

__device__ __forceinline__ void combine_max(float& mx, int& cnt, int& gt,
                                            float mx2, int cnt2, int gt2) {
    if (mx2 > mx) { mx = mx2; cnt = cnt2; gt = gt2; }
    else if (mx2 == mx) { cnt += cnt2; gt += gt2; }
}

// finalize + mean: 512 threads (8 waves); each 16-lane group reduces one
// sample's 16 partials (segmented butterfly, offsets 8/4/2/1)
__global__ __launch_bounds__(512) void k_final(const float* __restrict__ wsf,
                                               const int* __restrict__ wsi,
                                               float* __restrict__ out) {
    __shared__ float scores[NS];
    const int t = threadIdx.x;
    const int w = t >> 6, lane = t & 63;
    const int samp = (w << 2) + (lane >> 4);  // 8 waves x 4 samples
    const int pidx = lane & 15;
    const int idx = samp * PBLK + pidx;

    float s1  = wsf[OFF_S1  + idx];
    float s2  = wsf[OFF_S2  + idx];
    float dot = wsf[OFF_DOT + idx];
    float mx  = wsf[OFF_MX  + idx];
    int   cgt = wsi[OFF_CGT + idx];
    const int pk = wsi[OFF_PK + idx];
    int   cnt = pk >> 16;      // unpack: sample-level counts exceed 16 bits
    int   gt  = pk & 0xFFFF;

#pragma unroll
    for (int off = 8; off; off >>= 1) {      // stays within 16-lane group
        s1  += __shfl_xor(s1, off);
        s2  += __shfl_xor(s2, off);
        dot += __shfl_xor(dot, off);
        cgt += __shfl_xor(cgt, off);
        float m2 = __shfl_xor(mx, off);
        int   c2 = __shfl_xor(cnt, off);
        int   g2 = __shfl_xor(gt, off);
        combine_max(mx, cnt, gt, m2, c2, g2);
    }

    if (pidx == 0) {
        const int cle = NELEM - cgt;         // count(p <= 0.5)
        const long long corr = (long long)cle - (long long)cnt + 2LL * (long long)gt;
        float score = 2.0f * (dot + 1.0f) / (s1 + s2 + 1.0f);
        if (corr == 1) score = 1.0f;         // acc == 1.0 (probs.shape[1] == 1)
        scores[samp] = 1.0f - score;
    }

    __syncthreads();
    if (t < 64) {
        float v = (t < NS) ? scores[t] : 0.0f;
#pragma unroll
        for (int off = 32; off; off >>= 1) v += __shfl_xor(v, off);
        if (t == 0) out[0] = v * (1.0f / (float)NS);
    }
}

extern "C" void kernel_launch(void* const* d_in, const int* in_sizes, int n_in,
                              void* d_out, int out_size, void* d_ws, size_t ws_size,
                              hipStream_t stream) {
    const float* probs = (const float*)d_in[0];
    const float* tgts  = (const float*)d_in[1];
    float* wsf = (float*)d_ws;
    int*   wsi = (int*)d_ws;
    float* out = (float*)d_out;

    k_partial<<<GRID, TPB, 0, stream>>>(probs, tgts, wsf, wsi);
    k_final<<<1, 512, 0, stream>>>(wsf, wsi, out);
}